// Round 2
// baseline (2043.698 us; speedup 1.0000x reference)
//
#include <hip/hip_runtime.h>

#define NROWS 131072
#define DIM   512
#define CTXC  128
#define HIDN  2048
#define K1    384
#define DU    256
#define S_MAXF 5.0f

typedef _Float16 f16;
typedef _Float16 f16x2 __attribute__((ext_vector_type(2)));
typedef _Float16 f16x8 __attribute__((ext_vector_type(8)));
typedef float f32x4 __attribute__((ext_vector_type(4)));

#define A_STRIDE 392   // 384 + 8 halfs pad -> 784 B row stride (16B aligned, 2-way banks)
#define H_STRIDE 136   // 128 + 8 halfs pad -> 272 B row stride

// ---------------- prep: transpose + fp32->fp16 convert ----------------
// src [R][C] f32 row-major  ->  dst [C][R] f16
__global__ __launch_bounds__(256) void transpose_cvt(const float* __restrict__ src,
                                                     f16* __restrict__ dst,
                                                     int R, int C) {
    __shared__ float tile[32][33];
    int ct = blockIdx.x * 32, rt = blockIdx.y * 32;
    int tx = threadIdx.x & 31, ty = threadIdx.x >> 5;  // 32 x 8
#pragma unroll
    for (int i = 0; i < 32; i += 8)
        tile[ty + i][tx] = src[(size_t)(rt + ty + i) * C + ct + tx];
    __syncthreads();
#pragma unroll
    for (int i = 0; i < 32; i += 8)
        dst[(size_t)(ct + ty + i) * R + rt + tx] = (f16)tile[tx][ty + i];
}

// ---------------- fused coupling kernel ----------------
// 64 rows per block, 512 threads (8 waves: 2 M-waves x 4 N-waves).
// st accumulators: wave (wm,wn) owns rows wm*32..+32, s-cols wn*64..+64 and
// t-cols 256+wn*64..+64  (matched s/t pairs -> register-local epilogue).
__global__ __launch_bounds__(512) void fused_coupling(
    const float* __restrict__ x, const float* __restrict__ ctx,
    const f16* __restrict__ W1T,   // [2048][384] f16 (col-major of W1)
    const float* __restrict__ b1,
    const f16* __restrict__ W2T,   // [512][2048] f16 (col-major of W2)
    const float* __restrict__ b2,
    float* __restrict__ yout, float* __restrict__ logdet) {

    __shared__ f16 Alds[64 * A_STRIDE];  // 50176 B, resident st_in tile
    __shared__ f16 w1t[2 * 4096];        // 16384 B, [buf][part(4)][col(128)][8]
    __shared__ f16 w2t[2 * 16384];       // 65536 B, [buf][part(4)][col(512)][8]
    __shared__ f16 hlds[64 * H_STRIDE];  // 17408 B
    __shared__ float ldsum[64];

    const int t   = threadIdx.x;
    const int lane = t & 63;
    const int w   = t >> 6;
    const int wm  = w >> 2;   // 0..1
    const int wn  = w & 3;    // 0..3
    const int l15 = lane & 15;
    const int l4  = lane >> 4;
    const int r0  = blockIdx.x * 64;

    if (t < 64) ldsum[t] = 0.0f;

    // ---- stage A = [x_even | ctx] as f16, row-major [64][A_STRIDE] ----
    {
        int row = t & 63;
        int sub = t >> 6;  // 0..7
#pragma unroll
        for (int it = 0; it < 16; ++it) {
            int c4 = it * 8 + sub;  // float4 index 0..127
            float4 v = *(const float4*)(x + (size_t)(r0 + row) * DIM + c4 * 4);
            f16x2 h2 = { (f16)v.x, (f16)v.z };   // even cols 4c4, 4c4+2
            *(f16x2*)(Alds + row * A_STRIDE + c4 * 2) = h2;
        }
#pragma unroll
        for (int it = 0; it < 8; ++it) {
            int c2 = it * 8 + sub;  // float2 index 0..63
            float2 v = *(const float2*)(ctx + (size_t)(r0 + row) * CTXC + c2 * 2);
            f16x2 h2 = { (f16)v.x, (f16)v.y };
            *(f16x2*)(Alds + row * A_STRIDE + 256 + c2 * 2) = h2;
        }
    }

    f32x4 stacc[2][8];
#pragma unroll
    for (int i = 0; i < 2; ++i)
#pragma unroll
        for (int j = 0; j < 8; ++j)
            stacc[i][j] = (f32x4){0.f, 0.f, 0.f, 0.f};

    const int g1col = t & 127, g1part = t >> 7;

    for (int ht = 0; ht < 16; ++ht) {
        f32x4 hacc[2][2];
#pragma unroll
        for (int i = 0; i < 2; ++i)
#pragma unroll
            for (int j = 0; j < 2; ++j)
                hacc[i][j] = (f32x4){0.f, 0.f, 0.f, 0.f};

        // prologue: stage w1t buf0 (kk=0)
        {
            float4 p = *(const float4*)(W1T + (size_t)(ht * 128 + g1col) * K1 + g1part * 8);
            *(float4*)(w1t + g1part * 1024 + g1col * 8) = p;
        }
        // ---- GEMM1: h = A @ W1 over K1=384 (12 k-steps, dbuf) ----
        for (int kk = 0; kk < 12; ++kk) {
            __syncthreads();
            float4 nxt;
            if (kk < 11)
                nxt = *(const float4*)(W1T + (size_t)(ht * 128 + g1col) * K1 + (kk + 1) * 32 + g1part * 8);
            const f16* buf = w1t + (kk & 1) * 4096;
            f16x8 af[2], bf[2];
#pragma unroll
            for (int mf = 0; mf < 2; ++mf)
                af[mf] = *(const f16x8*)(Alds + (wm * 32 + mf * 16 + l15) * A_STRIDE + kk * 32 + l4 * 8);
#pragma unroll
            for (int nf = 0; nf < 2; ++nf)
                bf[nf] = *(const f16x8*)(buf + l4 * 1024 + (wn * 32 + nf * 16 + l15) * 8);
#pragma unroll
            for (int mf = 0; mf < 2; ++mf)
#pragma unroll
                for (int nf = 0; nf < 2; ++nf)
                    hacc[mf][nf] = __builtin_amdgcn_mfma_f32_16x16x32_f16(af[mf], bf[nf], hacc[mf][nf], 0, 0, 0);
            if (kk < 11)
                *(float4*)(w1t + ((kk + 1) & 1) * 4096 + g1part * 1024 + g1col * 8) = nxt;
        }

        // GEMM2 prologue loads (issued early, land after h-write)
        float4 p2[4];
#pragma unroll
        for (int i = 0; i < 4; ++i)
            p2[i] = *(const float4*)(W2T + (size_t)t * HIDN + ht * 128 + i * 8);

        // ---- h epilogue: +b1, relu, cvt f16 -> hlds ----
#pragma unroll
        for (int mf = 0; mf < 2; ++mf)
#pragma unroll
            for (int nf = 0; nf < 2; ++nf) {
                int col = wn * 32 + nf * 16 + l15;
                float bb = b1[ht * 128 + col];
#pragma unroll
                for (int r = 0; r < 4; ++r) {
                    int row = wm * 32 + mf * 16 + l4 * 4 + r;
                    float v = hacc[mf][nf][r] + bb;
                    hlds[row * H_STRIDE + col] = (f16)fmaxf(v, 0.f);
                }
            }
#pragma unroll
        for (int i = 0; i < 4; ++i)
            *(float4*)(w2t + i * 4096 + t * 8) = p2[i];
        __syncthreads();

        // ---- GEMM2 partial: stacc += relu(h) @ W2[tile] (4 k-steps, dbuf) ----
        for (int kk = 0; kk < 4; ++kk) {
            float4 n2[4];
            if (kk < 3) {
#pragma unroll
                for (int i = 0; i < 4; ++i)
                    n2[i] = *(const float4*)(W2T + (size_t)t * HIDN + ht * 128 + (kk + 1) * 32 + i * 8);
            }
            const f16* buf = w2t + (kk & 1) * 16384;
            f16x8 haf[2], wbf[8];
#pragma unroll
            for (int mf = 0; mf < 2; ++mf)
                haf[mf] = *(const f16x8*)(hlds + (wm * 32 + mf * 16 + l15) * H_STRIDE + kk * 32 + l4 * 8);
#pragma unroll
            for (int nf = 0; nf < 8; ++nf) {
                int col = (nf < 4) ? (wn * 64 + nf * 16 + l15)
                                   : (256 + wn * 64 + (nf - 4) * 16 + l15);
                wbf[nf] = *(const f16x8*)(buf + l4 * 4096 + col * 8);
            }
#pragma unroll
            for (int mf = 0; mf < 2; ++mf)
#pragma unroll
                for (int nf = 0; nf < 8; ++nf)
                    stacc[mf][nf] = __builtin_amdgcn_mfma_f32_16x16x32_f16(haf[mf], wbf[nf], stacc[mf][nf], 0, 0, 0);
            if (kk < 3) {
#pragma unroll
                for (int i = 0; i < 4; ++i)
                    *(float4*)(w2t + ((kk + 1) & 1) * 16384 + i * 4096 + t * 8) = n2[i];
            }
            __syncthreads();
        }
    }

    // ---- epilogue: s=tanh(st_s+b2)*5, y_odd = x_odd*exp(s)+t, y_even = x_even, logdet ----
#pragma unroll
    for (int mf = 0; mf < 2; ++mf) {
        float ldacc[4] = {0.f, 0.f, 0.f, 0.f};
#pragma unroll
        for (int nf = 0; nf < 4; ++nf) {
            int scol = wn * 64 + nf * 16 + l15;
            float bs = b2[scol];
            float bt = b2[DU + scol];
#pragma unroll
            for (int r = 0; r < 4; ++r) {
                int row = r0 + wm * 32 + mf * 16 + l4 * 4 + r;
                float sp = stacc[mf][nf][r] + bs;
                float tp = stacc[mf][nf + 4][r] + bt;
                float a  = fabsf(sp);
                float e2 = __expf(-2.f * a);
                float th = (1.f - e2) / (1.f + e2);
                float s  = S_MAXF * (sp < 0.f ? -th : th);
                float ex = __expf(s);
                const float2 xv = *(const float2*)(x + (size_t)row * DIM + 2 * scol);
                float2 yv;
                yv.x = xv.x;
                yv.y = xv.y * ex + tp;
                *(float2*)(yout + (size_t)row * DIM + 2 * scol) = yv;
                ldacc[r] += s;
            }
        }
#pragma unroll
        for (int r = 0; r < 4; ++r) {
            float v = ldacc[r];
            v += __shfl_xor(v, 1);
            v += __shfl_xor(v, 2);
            v += __shfl_xor(v, 4);
            v += __shfl_xor(v, 8);
            if (l15 == 0)
                atomicAdd(&ldsum[wm * 32 + mf * 16 + l4 * 4 + r], v);
        }
    }
    __syncthreads();
    if (t < 64) logdet[r0 + t] = ldsum[t];
}

extern "C" void kernel_launch(void* const* d_in, const int* in_sizes, int n_in,
                              void* d_out, int out_size, void* d_ws, size_t ws_size,
                              hipStream_t stream) {
    const float* x   = (const float*)d_in[0];
    const float* ctx = (const float*)d_in[1];
    const float* W1  = (const float*)d_in[2];
    const float* b1  = (const float*)d_in[3];
    const float* W2  = (const float*)d_in[4];
    const float* b2  = (const float*)d_in[5];

    float* y  = (float*)d_out;
    float* ld = y + (size_t)NROWS * DIM;

    f16* W1T = (f16*)d_ws;                       // [2048][384]
    f16* W2T = W1T + (size_t)HIDN * K1;          // [512][2048]   (total ~3.5 MB)

    // prep: transpose + convert weights to fp16 (every call; d_ws is re-poisoned)
    hipLaunchKernelGGL(transpose_cvt, dim3(HIDN / 32, K1 / 32), dim3(256), 0, stream,
                       W1, W1T, K1, HIDN);
    hipLaunchKernelGGL(transpose_cvt, dim3(DIM / 32, HIDN / 32), dim3(256), 0, stream,
                       W2, W2T, HIDN, DIM);

    hipLaunchKernelGGL(fused_coupling, dim3(NROWS / 64), dim3(512), 0, stream,
                       x, ctx, W1T, b1, W2T, b2, y, ld);
}